// Round 4
// baseline (222.633 us; speedup 1.0000x reference)
//
#include <hip/hip_runtime.h>

// Problem constants (fixed by the reference).
#define N_SPK 1024
#define M_UTT 32
#define D_EMB 512
#define NROWS (N_SPK * M_UTT)   // 32768

#define NEG_INF (-__builtin_inff())

using f16x8 = __attribute__((ext_vector_type(8))) _Float16;
using f32x4 = __attribute__((ext_vector_type(4))) float;

// ===========================================================================
// FAST PATH: split-f16 MFMA GEMM with in-register A-split.  ws ~6.6 MB.
// ===========================================================================

// Async global->LDS, 16 B per lane. Global addr is per-lane; LDS dest is
// wave-uniform base + lane*16.
__device__ __forceinline__ void gload16(const void* g, void* lds) {
    __builtin_amdgcn_global_load_lds(
        (const __attribute__((address_space(1))) void*)g,
        (__attribute__((address_space(3))) void*)lds, 16, 0, 0);
}

// ---------------------------------------------------------------------------
// prep: one block per speaker n (32 rows x 512 dims).
//  - nsq[row] = ||e_row||^2
//  - centroid (fp32 mean) -> chi/clo f16 split
//  - block 0 zeroes out[0] (rowloss atomic-accumulates into it later)
// Reads e exactly once; writes only 2.2 MB (no e-split materialization).
// ---------------------------------------------------------------------------
__global__ __launch_bounds__(256)
void prep_kernel(const float* __restrict__ e,
                 _Float16* __restrict__ chi, _Float16* __restrict__ clo,
                 float* __restrict__ nsq, float* __restrict__ out) {
    __shared__ float csum[4][D_EMB];   // 8 KiB
    const int n = blockIdx.x;
    const int wv = threadIdx.x >> 6, l = threadIdx.x & 63;

    if (n == 0 && threadIdx.x == 0) out[0] = 0.f;

    float cacc[8];
#pragma unroll
    for (int j = 0; j < 8; ++j) cacc[j] = 0.f;

#pragma unroll
    for (int mi = 0; mi < 8; ++mi) {
        const int m = mi * 4 + wv;
        const size_t row = (size_t)n * M_UTT + m;
        const float* p = e + row * D_EMB + l * 8;
        float4 x0 = *(const float4*)p;
        float4 x1 = *(const float4*)(p + 4);
        float xs[8] = {x0.x, x0.y, x0.z, x0.w, x1.x, x1.y, x1.z, x1.w};
        float ssq = 0.f;
#pragma unroll
        for (int j = 0; j < 8; ++j) {
            float x = xs[j];
            cacc[j] += x;
            ssq = __builtin_fmaf(x, x, ssq);
        }
#pragma unroll
        for (int off = 32; off; off >>= 1) ssq += __shfl_xor(ssq, off);
        if (l == 0) nsq[row] = ssq;
    }

#pragma unroll
    for (int j = 0; j < 8; ++j) csum[wv][l * 8 + j] = cacc[j];
    __syncthreads();
    for (int d = threadIdx.x; d < D_EMB; d += 256) {
        float c = (csum[0][d] + csum[1][d] + csum[2][d] + csum[3][d])
                  * (1.0f / M_UTT);
        _Float16 hh = (_Float16)c;
        chi[(size_t)n * D_EMB + d] = hh;
        clo[(size_t)n * D_EMB + d] = (_Float16)(c - (float)hh);
    }
}

// ---------------------------------------------------------------------------
// gemm_ls: 128x128 logit tile per block.  Per 64-k tile (8 tiles):
//   stage A as raw fp32 (32 KB, waves 0/1) + Bhi/Blo f16 (16 KB each,
//   waves 2/3) via global_load_lds; split A -> (ahi, alo) f16 in registers;
//   3 MFMA combos ahi*bhi + alo*bhi + ahi*blo, fp32 acc.  96 MFMA/barrier.
//
// A LDS: 128 rows x 16 chunks(16B); phys chunk = logical ^ (row&15).
// B LDS: 128 rows x 8 chunks(16B);  phys chunk = logical ^ (row&7).
// Both give <=2-way bank aliasing on fragment ds_read_b128 (free), with the
// permutation applied on the global source address so global_load_lds's
// uniform-base + lane*16 dest constraint holds.
//
// XCD swizzle: blk&7 = XCD (round-robin dispatch); each XCD owns 32 rt,
// walking ct fastest -> A working set per XCD fits its L2.
// ---------------------------------------------------------------------------
__global__ __launch_bounds__(256, 2)
void gemm_ls_kernel(const float* __restrict__ e,
                    const _Float16* __restrict__ chi,
                    const _Float16* __restrict__ clo,
                    const float* __restrict__ nsq,
                    const float* __restrict__ wp,
                    const float* __restrict__ bp,
                    float2* __restrict__ pm,
                    float* __restrict__ diagL) {
    __shared__ float    Af[128 * 64];   // 32 KiB (fp32 A tile)
    __shared__ _Float16 Bh[128 * 64];   // 16 KiB
    __shared__ _Float16 Bl[128 * 64];   // 16 KiB

    const int tid = threadIdx.x;
    const int wv = tid >> 6, l = tid & 63;
    const int wy = wv >> 1, wx = wv & 1;   // wave quadrant: rows wy*64+, cols wx*64+
    const int ln = l & 15, q = l >> 4;

    const int blk = blockIdx.x;
    const int ct = (blk >> 3) & 7;
    const int rt = (blk & 7) * 32 + (blk >> 6);
    const int r0 = rt * 128, c0 = ct * 128;

    f32x4 acc[4][4];
    f32x4 zz = {0.f, 0.f, 0.f, 0.f};
#pragma unroll
    for (int i = 0; i < 4; ++i)
#pragma unroll
        for (int j = 0; j < 4; ++j) acc[i][j] = zz;

    // Staging roles.
    const int arl = l >> 4, ac = l & 15;        // A: row-in-issue, chunk
    const int brl = l >> 3, bc = l & 7;         // B: row-in-issue, chunk
    const float* asrc = e + (size_t)(r0 + wv * 64) * D_EMB;          // wv<2
    const _Float16* bsrc = ((wv == 2) ? chi : clo) + (size_t)c0 * D_EMB;
    float* adst = Af + wv * 64 * 64;
    _Float16* bdst = (wv == 2) ? Bh : Bl;

    for (int kt = 0; kt < 8; ++kt) {
        __syncthreads();   // previous tile's ds_reads done before overwrite
        if (wv < 2) {
#pragma unroll
            for (int i = 0; i < 16; ++i) {
                int r = i * 4 + arl;                  // 0..63 in this half
                int gch = ac ^ (r & 15);
                gload16(asrc + (size_t)r * D_EMB + kt * 64 + gch * 4,
                        adst + i * 256);
            }
        } else {
#pragma unroll
            for (int i = 0; i < 16; ++i) {
                int r = i * 8 + brl;                  // 0..127
                int gch = bc ^ (r & 7);
                gload16(bsrc + (size_t)r * D_EMB + kt * 64 + gch * 8,
                        bdst + i * 512);
            }
        }
        __syncthreads();   // barrier semantics drain vmcnt

#pragma unroll
        for (int ks = 0; ks < 2; ++ks) {
            f16x8 ah[4], al[4], bh[4], bl4[4];
#pragma unroll
            for (int t = 0; t < 4; ++t) {
                const int m = wy * 64 + t * 16 + ln;
                const int ch0 = (ks * 8 + q * 2) ^ (m & 15);
                const int ch1 = (ks * 8 + q * 2 + 1) ^ (m & 15);
                f32x4 a0 = *(const f32x4*)&Af[m * 64 + ch0 * 4];
                f32x4 a1 = *(const f32x4*)&Af[m * 64 + ch1 * 4];
                float xs[8] = {a0[0], a0[1], a0[2], a0[3],
                               a1[0], a1[1], a1[2], a1[3]};
                f16x8 h, lo;
#pragma unroll
                for (int j = 0; j < 8; ++j) {
                    float x = xs[j];
                    _Float16 hh = (_Float16)x;
                    h[j] = hh;
                    lo[j] = (_Float16)(x - (float)hh);   // exact residual
                }
                ah[t] = h; al[t] = lo;
                const int mb = wx * 64 + t * 16 + ln;
                const int cb_ = (ks * 4 + q) ^ (mb & 7);
                bh[t]  = *(const f16x8*)&Bh[mb * 64 + cb_ * 8];
                bl4[t] = *(const f16x8*)&Bl[mb * 64 + cb_ * 8];
            }
#pragma unroll
            for (int i = 0; i < 4; ++i)
#pragma unroll
                for (int j = 0; j < 4; ++j)
                    acc[i][j] = __builtin_amdgcn_mfma_f32_16x16x32_f16(
                        ah[i], bh[j], acc[i][j], 0, 0, 0);
#pragma unroll
            for (int i = 0; i < 4; ++i)
#pragma unroll
                for (int j = 0; j < 4; ++j)
                    acc[i][j] = __builtin_amdgcn_mfma_f32_16x16x32_f16(
                        al[i], bh[j], acc[i][j], 0, 0, 0);
#pragma unroll
            for (int i = 0; i < 4; ++i)
#pragma unroll
                for (int j = 0; j < 4; ++j)
                    acc[i][j] = __builtin_amdgcn_mfma_f32_16x16x32_f16(
                        ah[i], bl4[j], acc[i][j], 0, 0, 0);
        }
    }

    // ---- Epilogue: logits, diag substitution, per-64-col (max,sumexp) ----
    const float w = wp[0], bb = bp[0];
    const bool isDiag = (ct == (rt >> 5));

#pragma unroll
    for (int mt = 0; mt < 4; ++mt) {
#pragma unroll
        for (int r = 0; r < 4; ++r) {
            const int grow = r0 + wy * 64 + mt * 16 + q * 4 + r;
            const float nsqv = isDiag ? nsq[grow] : 0.f;
            const int nloc = (grow >> 5) - c0;   // diag col, tile-local
            float lv[4];
#pragma unroll
            for (int nt = 0; nt < 4; ++nt) {
                float v = acc[mt][nt][r];
                float lg = __builtin_fmaf(w, v, bb);
                if (isDiag && (wx * 64 + nt * 16 + ln) == nloc) {
                    lg = __builtin_fmaf(
                        w, __builtin_fmaf(32.0f, v, nsqv * (1.0f / 31.0f)), bb);
                    diagL[grow] = lg;
                }
                lv[nt] = lg;
            }
            float mx = fmaxf(fmaxf(lv[0], lv[1]), fmaxf(lv[2], lv[3]));
#pragma unroll
            for (int off = 8; off; off >>= 1) mx = fmaxf(mx, __shfl_xor(mx, off));
            float ss = 0.f;
#pragma unroll
            for (int nt = 0; nt < 4; ++nt) ss += __expf(lv[nt] - mx);
#pragma unroll
            for (int off = 8; off; off >>= 1) ss += __shfl_xor(ss, off);
            if (ln == 0) {
                float2 v2; v2.x = mx; v2.y = ss;
                pm[(size_t)grow * 16 + ct * 2 + wx] = v2;
            }
        }
    }
}

// ---------------------------------------------------------------------------
// rowloss: merge 16 (m,s) partials per row -> loss_row, block-reduce, then
// one device-scope atomicAdd into out (pre-zeroed by prep).
// ---------------------------------------------------------------------------
__global__ void rowloss_kernel(const float2* __restrict__ pm,
                               const float* __restrict__ diagL,
                               float* __restrict__ out) {
    __shared__ float red[4];
    const int tid = threadIdx.x;
    const int row = blockIdx.x * 256 + tid;
    float M = NEG_INF, S = 0.f;
#pragma unroll
    for (int i = 0; i < 16; ++i) {
        float2 t = pm[(size_t)row * 16 + i];
        float nm = fmaxf(M, t.x);
        S = S * __expf(M - nm) + t.y * __expf(t.x - nm);
        M = nm;
    }
    float loss = M + __logf(S) - diagL[row];
#pragma unroll
    for (int off = 32; off; off >>= 1) loss += __shfl_xor(loss, off);
    if ((tid & 63) == 0) red[tid >> 6] = loss;
    __syncthreads();
    if (tid == 0)
        atomicAdd(out, (red[0] + red[1] + red[2] + red[3]) * (1.0f / NROWS));
}

// ===========================================================================
// FALLBACK PATH (round-1 fp32 vector kernels) — used if ws_size is too small.
// ===========================================================================

__global__ void centroid_kernel(const float* __restrict__ e,
                                float* __restrict__ cent) {
    int gid = blockIdx.x * 256 + threadIdx.x;
    int n = gid >> 9;
    int d = gid & 511;
    const float* p = e + ((size_t)n * M_UTT) * D_EMB + d;
    float s = 0.f;
#pragma unroll
    for (int m = 0; m < M_UTT; ++m) s += p[(size_t)m * D_EMB];
    cent[gid] = s * (1.0f / M_UTT);
}

__global__ void normsq_kernel(const float* __restrict__ e,
                              float* __restrict__ nsq) {
    int wv = threadIdx.x >> 6;
    int lane = threadIdx.x & 63;
    int row = blockIdx.x * 4 + wv;
    const float* p = e + (size_t)row * D_EMB + lane;
    float s = 0.f;
#pragma unroll
    for (int j = 0; j < 8; ++j) { float x = p[j * 64]; s += x * x; }
#pragma unroll
    for (int off = 32; off; off >>= 1) s += __shfl_xor(s, off);
    if (lane == 0) nsq[row] = s;
}

#define BR 64
#define BC 128
#define BK 16
#define TR 4
#define TC 8

__global__ __launch_bounds__(256, 2)
void ge2e_main(const float* __restrict__ e, const float* __restrict__ cent,
               const float* __restrict__ nsq, const float* __restrict__ wp,
               const float* __restrict__ bp, float* __restrict__ partials) {
    __shared__ float As[BK][BR];
    __shared__ float Bs[BK][BC];
    __shared__ float diagLs[BR];
    __shared__ float red[16];

    const int tid = threadIdx.x;
    const int tx = tid & 15;
    const int ty = tid >> 4;
    const int blk = blockIdx.x;
    const int r0 = blk * BR;

    const float w = *wp;
    const float bb = *bp;

    float m_run[TR], s_run[TR];
#pragma unroll
    for (int i = 0; i < TR; ++i) { m_run[i] = NEG_INF; s_run[i] = 0.f; }

    const int a_row = tid >> 2;
    const int a_k   = (tid & 3) * 4;
    const int b_col = tid >> 1;
    const int b_k   = (tid & 1) * 8;

    for (int ct = 0; ct < N_SPK / BC; ++ct) {
        const int c0 = ct * BC;
        float acc[TR][TC];
#pragma unroll
        for (int i = 0; i < TR; ++i)
#pragma unroll
            for (int j = 0; j < TC; ++j) acc[i][j] = 0.f;

        for (int kk = 0; kk < D_EMB; kk += BK) {
            __syncthreads();
            {
                float4 av = *(const float4*)(e + (size_t)(r0 + a_row) * D_EMB + kk + a_k);
                As[a_k + 0][a_row] = av.x;
                As[a_k + 1][a_row] = av.y;
                As[a_k + 2][a_row] = av.z;
                As[a_k + 3][a_row] = av.w;
            }
            {
                const float* bp0 = cent + (size_t)(c0 + b_col) * D_EMB + kk + b_k;
                float4 bv0 = *(const float4*)(bp0);
                float4 bv1 = *(const float4*)(bp0 + 4);
                Bs[b_k + 0][b_col] = bv0.x;
                Bs[b_k + 1][b_col] = bv0.y;
                Bs[b_k + 2][b_col] = bv0.z;
                Bs[b_k + 3][b_col] = bv0.w;
                Bs[b_k + 4][b_col] = bv1.x;
                Bs[b_k + 5][b_col] = bv1.y;
                Bs[b_k + 6][b_col] = bv1.z;
                Bs[b_k + 7][b_col] = bv1.w;
            }
            __syncthreads();

#pragma unroll
            for (int k = 0; k < BK; ++k) {
                float4 a4 = *(const float4*)&As[k][ty * TR];
                float4 b4a = *(const float4*)&Bs[k][tx * TC];
                float4 b4b = *(const float4*)&Bs[k][tx * TC + 4];
                float av[TR] = {a4.x, a4.y, a4.z, a4.w};
                float bv[TC] = {b4a.x, b4a.y, b4a.z, b4a.w,
                                b4b.x, b4b.y, b4b.z, b4b.w};
#pragma unroll
                for (int i = 0; i < TR; ++i)
#pragma unroll
                    for (int j = 0; j < TC; ++j)
                        acc[i][j] = __builtin_fmaf(av[i], bv[j], acc[i][j]);
            }
        }

#pragma unroll
        for (int i = 0; i < TR; ++i) {
            const int grow = r0 + ty * TR + i;
            const int dcol = grow >> 5;
            float lv[TC];
#pragma unroll
            for (int j = 0; j < TC; ++j) {
                const int gcol = c0 + tx * TC + j;
                float v = acc[i][j];
                float lg;
                if (gcol == dcol) {
                    lg = __builtin_fmaf(w, __builtin_fmaf(32.0f, v,
                             (1.0f / 31.0f) * nsq[grow]), bb);
                    diagLs[ty * TR + i] = lg;
                } else {
                    lg = __builtin_fmaf(w, v, bb);
                }
                lv[j] = lg;
            }
            float mx = lv[0];
#pragma unroll
            for (int j = 1; j < TC; ++j) mx = fmaxf(mx, lv[j]);
#pragma unroll
            for (int off = 8; off; off >>= 1) mx = fmaxf(mx, __shfl_xor(mx, off));
            float ss = 0.f;
#pragma unroll
            for (int j = 0; j < TC; ++j) ss += __expf(lv[j] - mx);
#pragma unroll
            for (int off = 8; off; off >>= 1) ss += __shfl_xor(ss, off);
            float nm = fmaxf(m_run[i], mx);
            s_run[i] = s_run[i] * __expf(m_run[i] - nm) + ss * __expf(mx - nm);
            m_run[i] = nm;
        }
    }

    __syncthreads();
    if (tx == 0) {
        float part = 0.f;
#pragma unroll
        for (int i = 0; i < TR; ++i) {
            const int lr = ty * TR + i;
            part += m_run[i] + __logf(s_run[i]) - diagLs[lr];
        }
        red[ty] = part;
    }
    __syncthreads();
    if (tid == 0) {
        float t = 0.f;
#pragma unroll
        for (int i = 0; i < 16; ++i) t += red[i];
        partials[blk] = t;
    }
}

__global__ void reduce_kernel(const float* __restrict__ partials,
                              float* __restrict__ out) {
    __shared__ float red[4];
    int tid = threadIdx.x;
    float v = partials[tid] + partials[tid + 256];
#pragma unroll
    for (int off = 32; off; off >>= 1) v += __shfl_xor(v, off);
    if ((tid & 63) == 0) red[tid >> 6] = v;
    __syncthreads();
    if (tid == 0)
        out[0] = (red[0] + red[1] + red[2] + red[3]) * (1.0f / NROWS);
}

// ===========================================================================

extern "C" void kernel_launch(void* const* d_in, const int* in_sizes, int n_in,
                              void* d_out, int out_size, void* d_ws, size_t ws_size,
                              hipStream_t stream) {
    const float* e  = (const float*)d_in[0];   // [1024,32,512] f32
    const float* wp = (const float*)d_in[1];   // scalar
    const float* bp = (const float*)d_in[2];   // scalar
    float* out = (float*)d_out;

    // Fast-path workspace layout (bytes, 256-aligned):
    //   chi 1048576 | clo 1048576 | nsq 131072 | pm 4194304 | diagL 131072
    const size_t NEED_FAST = 1048576ull * 2 + 131072ull + 4194304ull
                           + 131072ull;   // 6,553,600

    if (ws_size >= NEED_FAST) {
        char* base = (char*)d_ws;
        _Float16* chi = (_Float16*)(base);
        _Float16* clo = (_Float16*)(base + 1048576ull);
        float*    nsq = (float*)   (base + 2097152ull);
        float2*   pm  = (float2*)  (base + 2228224ull);
        float*    dgl = (float*)   (base + 6422528ull);

        prep_kernel<<<N_SPK, 256, 0, stream>>>(e, chi, clo, nsq, out);
        gemm_ls_kernel<<<2048, 256, 0, stream>>>(e, chi, clo, nsq,
                                                 wp, bp, pm, dgl);
        rowloss_kernel<<<NROWS / 256, 256, 0, stream>>>(pm, dgl, out);
    } else {
        float* ws = (float*)d_ws;
        float* cent     = ws;
        float* nsq      = ws + 524288;
        float* partials = ws + 524288 + 32768;

        centroid_kernel<<<N_SPK * D_EMB / 256, 256, 0, stream>>>(e, cent);
        normsq_kernel<<<NROWS / 4, 256, 0, stream>>>(e, nsq);
        ge2e_main<<<NROWS / BR, 256, 0, stream>>>(e, cent, nsq, wp, bp, partials);
        reduce_kernel<<<1, 256, 0, stream>>>(partials, out);
    }
}

// Round 5
// 160.019 us; speedup vs baseline: 1.3913x; 1.3913x over previous
//
#include <hip/hip_runtime.h>

// Problem constants (fixed by the reference).
#define N_SPK 1024
#define M_UTT 32
#define D_EMB 512
#define NROWS (N_SPK * M_UTT)   // 32768

#define NEG_INF (-__builtin_inff())

using f16x8 = __attribute__((ext_vector_type(8))) _Float16;
using f32x4 = __attribute__((ext_vector_type(4))) float;

// ===========================================================================
// FAST PATH: single-pass f16 MFMA GEMM + exact fp32 diagonal.  ws ~39 MB.
// ===========================================================================

// Async global->LDS, 16 B per lane. Global addr is per-lane; LDS dest is
// wave-uniform base + lane*16.
__device__ __forceinline__ void gload16(const void* g, void* lds) {
    __builtin_amdgcn_global_load_lds(
        (const __attribute__((address_space(1))) void*)g,
        (__attribute__((address_space(3))) void*)lds, 16, 0, 0);
}

// ---------------------------------------------------------------------------
// prep: one block per speaker n (32 rows x 512 dims).  Reads e ONCE.
//  - ehf[row] = (f16) e[row]                      (33.5 MB)
//  - ch[n]    = (f16) centroid                    (1 MB)
//  - dgl[row] = w*(e.sum + ||e||^2/31) + b  exact fp32 diag logit (131 KB)
//  - block 0 zeroes out[0] (rowloss atomic-accumulates into it)
// Row data is retained in registers across the centroid barrier so the
// diag dot needs no second global read.
// ---------------------------------------------------------------------------
__global__ __launch_bounds__(256)
void prep_kernel(const float* __restrict__ e,
                 _Float16* __restrict__ ehf, _Float16* __restrict__ ch,
                 float* __restrict__ dgl,
                 const float* __restrict__ wp, const float* __restrict__ bp,
                 float* __restrict__ out) {
    __shared__ float csum[4][D_EMB];   // 8 KiB
    const int n = blockIdx.x;
    const int wv = threadIdx.x >> 6, l = threadIdx.x & 63;

    if (n == 0 && threadIdx.x == 0) out[0] = 0.f;

    float xs[8][8];     // retained row data (lane's 8 dims x 8 rows)
    float ssq[8];       // per-row ||e||^2 (wave-uniform after butterfly)
    float cacc[8];
#pragma unroll
    for (int j = 0; j < 8; ++j) cacc[j] = 0.f;

#pragma unroll
    for (int mi = 0; mi < 8; ++mi) {
        const int m = mi * 4 + wv;
        const size_t row = (size_t)n * M_UTT + m;
        const float* p = e + row * D_EMB + l * 8;
        float4 x0 = *(const float4*)p;
        float4 x1 = *(const float4*)(p + 4);
        xs[mi][0] = x0.x; xs[mi][1] = x0.y; xs[mi][2] = x0.z; xs[mi][3] = x0.w;
        xs[mi][4] = x1.x; xs[mi][5] = x1.y; xs[mi][6] = x1.z; xs[mi][7] = x1.w;
        f16x8 h;
        float sq = 0.f;
#pragma unroll
        for (int j = 0; j < 8; ++j) {
            float x = xs[mi][j];
            h[j] = (_Float16)x;
            cacc[j] += x;
            sq = __builtin_fmaf(x, x, sq);
        }
        *(f16x8*)(ehf + row * D_EMB + l * 8) = h;
#pragma unroll
        for (int off = 32; off; off >>= 1) sq += __shfl_xor(sq, off);
        ssq[mi] = sq;
    }

#pragma unroll
    for (int j = 0; j < 8; ++j) csum[wv][l * 8 + j] = cacc[j];
    __syncthreads();
    for (int d = threadIdx.x; d < D_EMB; d += 256) {
        float s = csum[0][d] + csum[1][d] + csum[2][d] + csum[3][d];
        csum[0][d] = s;                               // full speaker sum
        ch[(size_t)n * D_EMB + d] = (_Float16)(s * (1.0f / M_UTT));
    }
    __syncthreads();

    // Exact fp32 diag: dgl[row] = w*(e.sum + ssq/31) + b.
    float sv[8];
#pragma unroll
    for (int j = 0; j < 8; ++j) sv[j] = csum[0][l * 8 + j];
    const float w = wp[0], bb = bp[0];
#pragma unroll
    for (int mi = 0; mi < 8; ++mi) {
        float dg = 0.f;
#pragma unroll
        for (int j = 0; j < 8; ++j) dg = __builtin_fmaf(xs[mi][j], sv[j], dg);
#pragma unroll
        for (int off = 32; off; off >>= 1) dg += __shfl_xor(dg, off);
        if (l == 0) {
            const size_t row = (size_t)n * M_UTT + mi * 4 + wv;
            dgl[row] = __builtin_fmaf(w, dg + ssq[mi] * (1.0f / 31.0f), bb);
        }
    }
}

// ---------------------------------------------------------------------------
// gemm_ls: 128x128 logit tile per block, single-pass f16 MFMA.  Per 64-half
// k-tile (8 tiles): stage Ah (16 KB, waves 0/1) + Bh (16 KB, waves 2/3) via
// global_load_lds; 2 K-steps x 16 MFMA = 32 MFMA/barrier/wave.  32 KB LDS.
//
// LDS layout per buffer: 128 rows x 8 chunks(16B); phys chunk = c ^ (row&7)
// (permutation applied on the global source address, so global_load_lds's
// uniform-base + lane*16 dest holds; fragment ds_read_b128 is 2-way = free).
//
// Epilogue: logits, diag substitution from exact dgl[], per-64-col
// (max,sumexp) partials -> pm[row][ct*2+wx].
//
// XCD swizzle: blk&7 = XCD (round-robin dispatch); each XCD owns 32 rt,
// walking ct fastest -> A working set per XCD fits its L2.
// ---------------------------------------------------------------------------
__global__ __launch_bounds__(256, 2)
void gemm_ls_kernel(const _Float16* __restrict__ ehf,
                    const _Float16* __restrict__ ch,
                    const float* __restrict__ dgl,
                    const float* __restrict__ wp,
                    const float* __restrict__ bp,
                    float2* __restrict__ pm) {
    __shared__ _Float16 Ah[128 * 64];   // 16 KiB
    __shared__ _Float16 Bh[128 * 64];   // 16 KiB

    const int tid = threadIdx.x;
    const int wv = tid >> 6, l = tid & 63;
    const int wy = wv >> 1, wx = wv & 1;   // wave quadrant: rows wy*64+, cols wx*64+
    const int ln = l & 15, q = l >> 4;

    const int blk = blockIdx.x;
    const int ct = (blk >> 3) & 7;
    const int rt = (blk & 7) * 32 + (blk >> 6);
    const int r0 = rt * 128, c0 = ct * 128;

    f32x4 acc[4][4];
    f32x4 zz = {0.f, 0.f, 0.f, 0.f};
#pragma unroll
    for (int i = 0; i < 4; ++i)
#pragma unroll
        for (int j = 0; j < 4; ++j) acc[i][j] = zz;

    // Staging roles: waves 0,1 -> Ah halves; waves 2,3 -> Bh halves.
    const int half = wv & 1;                 // which 64-row half this wave fills
    const _Float16* src = (wv < 2)
        ? ehf + (size_t)(r0 + half * 64) * D_EMB
        : ch  + (size_t)(c0 + half * 64) * D_EMB;
    _Float16* dst = ((wv < 2) ? Ah : Bh) + half * 64 * 64;
    const int srl = l >> 3;                  // row within 8-row issue group
    const int sc  = l & 7;                   // physical chunk this lane fills

    // Per-lane fragment LDS offsets (halves), fixed across k-tiles.
    int offA[2][4], offB[2][4];
#pragma unroll
    for (int ks = 0; ks < 2; ++ks)
#pragma unroll
        for (int t = 0; t < 4; ++t) {
            int m = wy * 64 + t * 16 + ln;
            offA[ks][t] = m * 64 + (((ks * 4 + q) ^ (m & 7)) * 8);
            int mb = wx * 64 + t * 16 + ln;
            offB[ks][t] = mb * 64 + (((ks * 4 + q) ^ (mb & 7)) * 8);
        }

    for (int kt = 0; kt < 8; ++kt) {
        __syncthreads();   // previous tile's ds_reads done before overwrite
#pragma unroll
        for (int i = 0; i < 8; ++i) {
            int r = i * 8 + srl;                  // 0..63 local row
            int gch = sc ^ (r & 7);               // content k-chunk
            gload16(src + (size_t)r * D_EMB + kt * 64 + gch * 8,
                    dst + i * 512);
        }
        __syncthreads();   // barrier semantics drain vmcnt

#pragma unroll
        for (int ks = 0; ks < 2; ++ks) {
            f16x8 af[4], bf[4];
#pragma unroll
            for (int t = 0; t < 4; ++t) af[t] = *(const f16x8*)&Ah[offA[ks][t]];
#pragma unroll
            for (int t = 0; t < 4; ++t) bf[t] = *(const f16x8*)&Bh[offB[ks][t]];
#pragma unroll
            for (int i = 0; i < 4; ++i)
#pragma unroll
                for (int j = 0; j < 4; ++j)
                    acc[i][j] = __builtin_amdgcn_mfma_f32_16x16x32_f16(
                        af[i], bf[j], acc[i][j], 0, 0, 0);
        }
    }

    // ---- Epilogue: logits, exact-diag substitution, per-64-col (max,sumexp) --
    const float w = wp[0], bb = bp[0];
    const bool isDiag = (ct == (rt >> 5));

#pragma unroll
    for (int mt = 0; mt < 4; ++mt) {
#pragma unroll
        for (int r = 0; r < 4; ++r) {
            const int grow = r0 + wy * 64 + mt * 16 + q * 4 + r;
            const float dglv = isDiag ? dgl[grow] : 0.f;
            const int nloc = (grow >> 5) - c0;   // diag col, tile-local
            float lv[4];
#pragma unroll
            for (int nt = 0; nt < 4; ++nt) {
                float lg = __builtin_fmaf(w, acc[mt][nt][r], bb);
                if (isDiag && (wx * 64 + nt * 16 + ln) == nloc) lg = dglv;
                lv[nt] = lg;
            }
            float mx = fmaxf(fmaxf(lv[0], lv[1]), fmaxf(lv[2], lv[3]));
#pragma unroll
            for (int off = 8; off; off >>= 1) mx = fmaxf(mx, __shfl_xor(mx, off));
            float ss = 0.f;
#pragma unroll
            for (int nt = 0; nt < 4; ++nt) ss += __expf(lv[nt] - mx);
#pragma unroll
            for (int off = 8; off; off >>= 1) ss += __shfl_xor(ss, off);
            if (ln == 0) {
                float2 v2; v2.x = mx; v2.y = ss;
                pm[(size_t)grow * 16 + ct * 2 + wx] = v2;
            }
        }
    }
}

// ---------------------------------------------------------------------------
// rowloss: merge 16 (m,s) partials per row -> loss_row, block-reduce, then
// one device-scope atomicAdd into out (pre-zeroed by prep).
// ---------------------------------------------------------------------------
__global__ void rowloss_kernel(const float2* __restrict__ pm,
                               const float* __restrict__ dgl,
                               float* __restrict__ out) {
    __shared__ float red[4];
    const int tid = threadIdx.x;
    const int row = blockIdx.x * 256 + tid;
    float M = NEG_INF, S = 0.f;
#pragma unroll
    for (int i = 0; i < 16; ++i) {
        float2 t = pm[(size_t)row * 16 + i];
        float nm = fmaxf(M, t.x);
        S = S * __expf(M - nm) + t.y * __expf(t.x - nm);
        M = nm;
    }
    float loss = M + __logf(S) - dgl[row];
#pragma unroll
    for (int off = 32; off; off >>= 1) loss += __shfl_xor(loss, off);
    if ((tid & 63) == 0) red[tid >> 6] = loss;
    __syncthreads();
    if (tid == 0)
        atomicAdd(out, (red[0] + red[1] + red[2] + red[3]) * (1.0f / NROWS));
}

// ===========================================================================
// FALLBACK PATH (round-1 fp32 vector kernels) — used if ws_size is too small.
// ===========================================================================

__global__ void centroid_kernel(const float* __restrict__ e,
                                float* __restrict__ cent) {
    int gid = blockIdx.x * 256 + threadIdx.x;
    int n = gid >> 9;
    int d = gid & 511;
    const float* p = e + ((size_t)n * M_UTT) * D_EMB + d;
    float s = 0.f;
#pragma unroll
    for (int m = 0; m < M_UTT; ++m) s += p[(size_t)m * D_EMB];
    cent[gid] = s * (1.0f / M_UTT);
}

__global__ void normsq_kernel(const float* __restrict__ e,
                              float* __restrict__ nsq) {
    int wv = threadIdx.x >> 6;
    int lane = threadIdx.x & 63;
    int row = blockIdx.x * 4 + wv;
    const float* p = e + (size_t)row * D_EMB + lane;
    float s = 0.f;
#pragma unroll
    for (int j = 0; j < 8; ++j) { float x = p[j * 64]; s += x * x; }
#pragma unroll
    for (int off = 32; off; off >>= 1) s += __shfl_xor(s, off);
    if (lane == 0) nsq[row] = s;
}

#define BR 64
#define BC 128
#define BK 16
#define TR 4
#define TC 8

__global__ __launch_bounds__(256, 2)
void ge2e_main(const float* __restrict__ e, const float* __restrict__ cent,
               const float* __restrict__ nsq, const float* __restrict__ wp,
               const float* __restrict__ bp, float* __restrict__ partials) {
    __shared__ float As[BK][BR];
    __shared__ float Bs[BK][BC];
    __shared__ float diagLs[BR];
    __shared__ float red[16];

    const int tid = threadIdx.x;
    const int tx = tid & 15;
    const int ty = tid >> 4;
    const int blk = blockIdx.x;
    const int r0 = blk * BR;

    const float w = *wp;
    const float bb = *bp;

    float m_run[TR], s_run[TR];
#pragma unroll
    for (int i = 0; i < TR; ++i) { m_run[i] = NEG_INF; s_run[i] = 0.f; }

    const int a_row = tid >> 2;
    const int a_k   = (tid & 3) * 4;
    const int b_col = tid >> 1;
    const int b_k   = (tid & 1) * 8;

    for (int ct = 0; ct < N_SPK / BC; ++ct) {
        const int c0 = ct * BC;
        float acc[TR][TC];
#pragma unroll
        for (int i = 0; i < TR; ++i)
#pragma unroll
            for (int j = 0; j < TC; ++j) acc[i][j] = 0.f;

        for (int kk = 0; kk < D_EMB; kk += BK) {
            __syncthreads();
            {
                float4 av = *(const float4*)(e + (size_t)(r0 + a_row) * D_EMB + kk + a_k);
                As[a_k + 0][a_row] = av.x;
                As[a_k + 1][a_row] = av.y;
                As[a_k + 2][a_row] = av.z;
                As[a_k + 3][a_row] = av.w;
            }
            {
                const float* bp0 = cent + (size_t)(c0 + b_col) * D_EMB + kk + b_k;
                float4 bv0 = *(const float4*)(bp0);
                float4 bv1 = *(const float4*)(bp0 + 4);
                Bs[b_k + 0][b_col] = bv0.x;
                Bs[b_k + 1][b_col] = bv0.y;
                Bs[b_k + 2][b_col] = bv0.z;
                Bs[b_k + 3][b_col] = bv0.w;
                Bs[b_k + 4][b_col] = bv1.x;
                Bs[b_k + 5][b_col] = bv1.y;
                Bs[b_k + 6][b_col] = bv1.z;
                Bs[b_k + 7][b_col] = bv1.w;
            }
            __syncthreads();

#pragma unroll
            for (int k = 0; k < BK; ++k) {
                float4 a4 = *(const float4*)&As[k][ty * TR];
                float4 b4a = *(const float4*)&Bs[k][tx * TC];
                float4 b4b = *(const float4*)&Bs[k][tx * TC + 4];
                float av[TR] = {a4.x, a4.y, a4.z, a4.w};
                float bv[TC] = {b4a.x, b4a.y, b4a.z, b4a.w,
                                b4b.x, b4b.y, b4b.z, b4b.w};
#pragma unroll
                for (int i = 0; i < TR; ++i)
#pragma unroll
                    for (int j = 0; j < TC; ++j)
                        acc[i][j] = __builtin_fmaf(av[i], bv[j], acc[i][j]);
            }
        }

#pragma unroll
        for (int i = 0; i < TR; ++i) {
            const int grow = r0 + ty * TR + i;
            const int dcol = grow >> 5;
            float lv[TC];
#pragma unroll
            for (int j = 0; j < TC; ++j) {
                const int gcol = c0 + tx * TC + j;
                float v = acc[i][j];
                float lg;
                if (gcol == dcol) {
                    lg = __builtin_fmaf(w, __builtin_fmaf(32.0f, v,
                             (1.0f / 31.0f) * nsq[grow]), bb);
                    diagLs[ty * TR + i] = lg;
                } else {
                    lg = __builtin_fmaf(w, v, bb);
                }
                lv[j] = lg;
            }
            float mx = lv[0];
#pragma unroll
            for (int j = 1; j < TC; ++j) mx = fmaxf(mx, lv[j]);
#pragma unroll
            for (int off = 8; off; off >>= 1) mx = fmaxf(mx, __shfl_xor(mx, off));
            float ss = 0.f;
#pragma unroll
            for (int j = 0; j < TC; ++j) ss += __expf(lv[j] - mx);
#pragma unroll
            for (int off = 8; off; off >>= 1) ss += __shfl_xor(ss, off);
            float nm = fmaxf(m_run[i], mx);
            s_run[i] = s_run[i] * __expf(m_run[i] - nm) + ss * __expf(mx - nm);
            m_run[i] = nm;
        }
    }

    __syncthreads();
    if (tx == 0) {
        float part = 0.f;
#pragma unroll
        for (int i = 0; i < TR; ++i) {
            const int lr = ty * TR + i;
            part += m_run[i] + __logf(s_run[i]) - diagLs[lr];
        }
        red[ty] = part;
    }
    __syncthreads();
    if (tid == 0) {
        float t = 0.f;
#pragma unroll
        for (int i = 0; i < 16; ++i) t += red[i];
        partials[blk] = t;
    }
}

__global__ void reduce_kernel(const float* __restrict__ partials,
                              float* __restrict__ out) {
    __shared__ float red[4];
    int tid = threadIdx.x;
    float v = partials[tid] + partials[tid + 256];
#pragma unroll
    for (int off = 32; off; off >>= 1) v += __shfl_xor(v, off);
    if ((tid & 63) == 0) red[tid >> 6] = v;
    __syncthreads();
    if (tid == 0)
        out[0] = (red[0] + red[1] + red[2] + red[3]) * (1.0f / NROWS);
}

// ===========================================================================

extern "C" void kernel_launch(void* const* d_in, const int* in_sizes, int n_in,
                              void* d_out, int out_size, void* d_ws, size_t ws_size,
                              hipStream_t stream) {
    const float* e  = (const float*)d_in[0];   // [1024,32,512] f32
    const float* wp = (const float*)d_in[1];   // scalar
    const float* bp = (const float*)d_in[2];   // scalar
    float* out = (float*)d_out;

    // Fast-path workspace layout (bytes, 256-aligned):
    //   ehf 33554432 | ch 1048576 | dgl 131072 | pm 4194304
    const size_t NEED_FAST = 33554432ull + 1048576ull + 131072ull
                           + 4194304ull;   // 38,928,384

    if (ws_size >= NEED_FAST) {
        char* base = (char*)d_ws;
        _Float16* ehf = (_Float16*)(base);
        _Float16* ch  = (_Float16*)(base + 33554432ull);
        float*    dgl = (float*)   (base + 34603008ull);
        float2*   pm  = (float2*)  (base + 34734080ull);

        prep_kernel<<<N_SPK, 256, 0, stream>>>(e, ehf, ch, dgl, wp, bp, out);
        gemm_ls_kernel<<<2048, 256, 0, stream>>>(ehf, ch, dgl, wp, bp, pm);
        rowloss_kernel<<<NROWS / 256, 256, 0, stream>>>(pm, dgl, out);
    } else {
        float* ws = (float*)d_ws;
        float* cent     = ws;
        float* nsq      = ws + 524288;
        float* partials = ws + 524288 + 32768;

        centroid_kernel<<<N_SPK * D_EMB / 256, 256, 0, stream>>>(e, cent);
        normsq_kernel<<<NROWS / 4, 256, 0, stream>>>(e, nsq);
        ge2e_main<<<NROWS / BR, 256, 0, stream>>>(e, cent, nsq, wp, bp, partials);
        reduce_kernel<<<1, 256, 0, stream>>>(partials, out);
    }
}

// Round 7
// 157.112 us; speedup vs baseline: 1.4170x; 1.0185x over previous
//
#include <hip/hip_runtime.h>

// Problem constants (fixed by the reference).
#define N_SPK 1024
#define M_UTT 32
#define D_EMB 512
#define NROWS (N_SPK * M_UTT)   // 32768

#define NEG_INF (-__builtin_inff())

using f16x8 = __attribute__((ext_vector_type(8))) _Float16;
using f32x4 = __attribute__((ext_vector_type(4))) float;

// ===========================================================================
// FAST PATH: single-pass f16 MFMA GEMM + exact fp32 diagonal.  ws ~39 MB.
//
// NOTE (round-6 lesson): the per-row softmax MUST carry a running max.
// The true loss (~0.00467) is dominated by ~one extreme row whose off-diag
// logits exceed its diag logit by ~150 nats; any representation that
// exponentiates relative to a fixed reference (e.g. dgl) overflows fp32.
// pm[row] = per-64-col (max, sumexp) partials is load-bearing.
// ===========================================================================

// Async global->LDS, 16 B per lane. Global addr is per-lane; LDS dest is
// wave-uniform base + lane*16.
__device__ __forceinline__ void gload16(const void* g, void* lds) {
    __builtin_amdgcn_global_load_lds(
        (const __attribute__((address_space(1))) void*)g,
        (__attribute__((address_space(3))) void*)lds, 16, 0, 0);
}

// ---------------------------------------------------------------------------
// prep: one block per speaker n (32 rows x 512 dims).  Reads e ONCE.
//  - ehf[row] = (f16) e[row]                      (33.5 MB)
//  - ch[n]    = (f16) centroid                    (1 MB)
//  - dgl[row] = w*(e.sum + ||e||^2/31) + b  exact fp32 diag logit (131 KB)
//  - block 0 zeroes out[0] (rowloss atomic-accumulates into it)
// ---------------------------------------------------------------------------
__global__ __launch_bounds__(256)
void prep_kernel(const float* __restrict__ e,
                 _Float16* __restrict__ ehf, _Float16* __restrict__ ch,
                 float* __restrict__ dgl,
                 const float* __restrict__ wp, const float* __restrict__ bp,
                 float* __restrict__ out) {
    __shared__ float csum[4][D_EMB];   // 8 KiB
    const int n = blockIdx.x;
    const int wv = threadIdx.x >> 6, l = threadIdx.x & 63;

    if (n == 0 && threadIdx.x == 0) out[0] = 0.f;

    float xs[8][8];     // retained row data (lane's 8 dims x 8 rows)
    float ssq[8];       // per-row ||e||^2 (wave-uniform after butterfly)
    float cacc[8];
#pragma unroll
    for (int j = 0; j < 8; ++j) cacc[j] = 0.f;

#pragma unroll
    for (int mi = 0; mi < 8; ++mi) {
        const int m = mi * 4 + wv;
        const size_t row = (size_t)n * M_UTT + m;
        const float* p = e + row * D_EMB + l * 8;
        float4 x0 = *(const float4*)p;
        float4 x1 = *(const float4*)(p + 4);
        xs[mi][0] = x0.x; xs[mi][1] = x0.y; xs[mi][2] = x0.z; xs[mi][3] = x0.w;
        xs[mi][4] = x1.x; xs[mi][5] = x1.y; xs[mi][6] = x1.z; xs[mi][7] = x1.w;
        f16x8 h;
        float sq = 0.f;
#pragma unroll
        for (int j = 0; j < 8; ++j) {
            float x = xs[mi][j];
            h[j] = (_Float16)x;
            cacc[j] += x;
            sq = __builtin_fmaf(x, x, sq);
        }
        *(f16x8*)(ehf + row * D_EMB + l * 8) = h;
#pragma unroll
        for (int off = 32; off; off >>= 1) sq += __shfl_xor(sq, off);
        ssq[mi] = sq;
    }

#pragma unroll
    for (int j = 0; j < 8; ++j) csum[wv][l * 8 + j] = cacc[j];
    __syncthreads();
    for (int d = threadIdx.x; d < D_EMB; d += 256) {
        float s = csum[0][d] + csum[1][d] + csum[2][d] + csum[3][d];
        csum[0][d] = s;                               // full speaker sum
        ch[(size_t)n * D_EMB + d] = (_Float16)(s * (1.0f / M_UTT));
    }
    __syncthreads();

    // Exact fp32 diag: dgl[row] = w*(e.sum + ssq/31) + b.
    float sv[8];
#pragma unroll
    for (int j = 0; j < 8; ++j) sv[j] = csum[0][l * 8 + j];
    const float w = wp[0], bb = bp[0];
#pragma unroll
    for (int mi = 0; mi < 8; ++mi) {
        float dg = 0.f;
#pragma unroll
        for (int j = 0; j < 8; ++j) dg = __builtin_fmaf(xs[mi][j], sv[j], dg);
#pragma unroll
        for (int off = 32; off; off >>= 1) dg += __shfl_xor(dg, off);
        if (l == 0) {
            const size_t row = (size_t)n * M_UTT + mi * 4 + wv;
            dgl[row] = __builtin_fmaf(w, dg + ssq[mi] * (1.0f / 31.0f), bb);
        }
    }
}

// ---------------------------------------------------------------------------
// gemm_ls: 128x128 logit tile per block, single-pass f16 MFMA.  Per 64-half
// k-tile (8 tiles): stage Ah (16 KB, waves 0/1) + Bh (16 KB, waves 2/3) via
// global_load_lds; 2 K-steps x 16 MFMA = 32 MFMA/barrier/wave.  32 KB LDS.
//
// LDS layout per buffer: 128 rows x 8 chunks(16B); phys chunk = c ^ (row&7)
// (permutation applied on the global source address, so global_load_lds's
// uniform-base + lane*16 dest holds; fragment ds_read_b128 is 2-way = free).
//
// Epilogue: logits, diag substitution from exact dgl[], per-64-col
// (max,sumexp) partials -> pm[row][ct*2+wx].  (max-carrying: see file note)
//
// XCD swizzle: blk&7 = XCD (round-robin dispatch); each XCD owns 32 rt,
// walking ct fastest -> A working set per XCD fits its L2.
// launch_bounds(256,4): VGPR 64 / LDS 32 KB allow 4 blocks/CU; co-resident
// blocks hide each other's barrier drains (m114 MFMA+VALU overlap).
// ---------------------------------------------------------------------------
__global__ __launch_bounds__(256, 4)
void gemm_ls_kernel(const _Float16* __restrict__ ehf,
                    const _Float16* __restrict__ ch,
                    const float* __restrict__ dgl,
                    const float* __restrict__ wp,
                    const float* __restrict__ bp,
                    float2* __restrict__ pm) {
    __shared__ _Float16 Ah[128 * 64];   // 16 KiB
    __shared__ _Float16 Bh[128 * 64];   // 16 KiB

    const int tid = threadIdx.x;
    const int wv = tid >> 6, l = tid & 63;
    const int wy = wv >> 1, wx = wv & 1;   // wave quadrant: rows wy*64+, cols wx*64+
    const int ln = l & 15, q = l >> 4;

    const int blk = blockIdx.x;
    const int ct = (blk >> 3) & 7;
    const int rt = (blk & 7) * 32 + (blk >> 6);
    const int r0 = rt * 128, c0 = ct * 128;

    f32x4 acc[4][4];
    f32x4 zz = {0.f, 0.f, 0.f, 0.f};
#pragma unroll
    for (int i = 0; i < 4; ++i)
#pragma unroll
        for (int j = 0; j < 4; ++j) acc[i][j] = zz;

    // Staging roles: waves 0,1 -> Ah halves; waves 2,3 -> Bh halves.
    const int half = wv & 1;                 // which 64-row half this wave fills
    const _Float16* src = (wv < 2)
        ? ehf + (size_t)(r0 + half * 64) * D_EMB
        : ch  + (size_t)(c0 + half * 64) * D_EMB;
    _Float16* dst = ((wv < 2) ? Ah : Bh) + half * 64 * 64;
    const int srl = l >> 3;                  // row within 8-row issue group
    const int sc  = l & 7;                   // physical chunk this lane fills

    // Per-lane fragment LDS offsets (halves), fixed across k-tiles.
    int offA[2][4], offB[2][4];
#pragma unroll
    for (int ks = 0; ks < 2; ++ks)
#pragma unroll
        for (int t = 0; t < 4; ++t) {
            int m = wy * 64 + t * 16 + ln;
            offA[ks][t] = m * 64 + (((ks * 4 + q) ^ (m & 7)) * 8);
            int mb = wx * 64 + t * 16 + ln;
            offB[ks][t] = mb * 64 + (((ks * 4 + q) ^ (mb & 7)) * 8);
        }

    for (int kt = 0; kt < 8; ++kt) {
        __syncthreads();   // previous tile's ds_reads done before overwrite
#pragma unroll
        for (int i = 0; i < 8; ++i) {
            int r = i * 8 + srl;                  // 0..63 local row
            int gch = sc ^ (r & 7);               // content k-chunk
            gload16(src + (size_t)r * D_EMB + kt * 64 + gch * 8,
                    dst + i * 512);
        }
        __syncthreads();   // barrier semantics drain vmcnt

#pragma unroll
        for (int ks = 0; ks < 2; ++ks) {
            f16x8 af[4], bf[4];
#pragma unroll
            for (int t = 0; t < 4; ++t) af[t] = *(const f16x8*)&Ah[offA[ks][t]];
#pragma unroll
            for (int t = 0; t < 4; ++t) bf[t] = *(const f16x8*)&Bh[offB[ks][t]];
#pragma unroll
            for (int i = 0; i < 4; ++i)
#pragma unroll
                for (int j = 0; j < 4; ++j)
                    acc[i][j] = __builtin_amdgcn_mfma_f32_16x16x32_f16(
                        af[i], bf[j], acc[i][j], 0, 0, 0);
        }
    }

    // ---- Epilogue: logits, exact-diag substitution, per-64-col (max,sumexp) --
    const float w = wp[0], bb = bp[0];
    const bool isDiag = (ct == (rt >> 5));

#pragma unroll
    for (int mt = 0; mt < 4; ++mt) {
#pragma unroll
        for (int r = 0; r < 4; ++r) {
            const int grow = r0 + wy * 64 + mt * 16 + q * 4 + r;
            const float dglv = isDiag ? dgl[grow] : 0.f;
            const int nloc = (grow >> 5) - c0;   // diag col, tile-local
            float lv[4];
#pragma unroll
            for (int nt = 0; nt < 4; ++nt) {
                float lg = __builtin_fmaf(w, acc[mt][nt][r], bb);
                if (isDiag && (wx * 64 + nt * 16 + ln) == nloc) lg = dglv;
                lv[nt] = lg;
            }
            float mx = fmaxf(fmaxf(lv[0], lv[1]), fmaxf(lv[2], lv[3]));
#pragma unroll
            for (int off = 8; off; off >>= 1) mx = fmaxf(mx, __shfl_xor(mx, off));
            float ss = 0.f;
#pragma unroll
            for (int nt = 0; nt < 4; ++nt) ss += __expf(lv[nt] - mx);
#pragma unroll
            for (int off = 8; off; off >>= 1) ss += __shfl_xor(ss, off);
            if (ln == 0) {
                float2 v2; v2.x = mx; v2.y = ss;
                pm[(size_t)grow * 16 + ct * 2 + wx] = v2;
            }
        }
    }
}

// ---------------------------------------------------------------------------
// rowloss: merge 16 (m,s) partials per row -> loss_row, block-reduce, then
// one device-scope atomicAdd into out (pre-zeroed by prep).
// ---------------------------------------------------------------------------
__global__ void rowloss_kernel(const float2* __restrict__ pm,
                               const float* __restrict__ dgl,
                               float* __restrict__ out) {
    __shared__ float red[4];
    const int tid = threadIdx.x;
    const int row = blockIdx.x * 256 + tid;
    float M = NEG_INF, S = 0.f;
#pragma unroll
    for (int i = 0; i < 16; ++i) {
        float2 t = pm[(size_t)row * 16 + i];
        float nm = fmaxf(M, t.x);
        S = S * __expf(M - nm) + t.y * __expf(t.x - nm);
        M = nm;
    }
    float loss = M + __logf(S) - dgl[row];
#pragma unroll
    for (int off = 32; off; off >>= 1) loss += __shfl_xor(loss, off);
    if ((tid & 63) == 0) red[tid >> 6] = loss;
    __syncthreads();
    if (tid == 0)
        atomicAdd(out, (red[0] + red[1] + red[2] + red[3]) * (1.0f / NROWS));
}

// ===========================================================================
// FALLBACK PATH (round-1 fp32 vector kernels) — used if ws_size is too small.
// ===========================================================================

__global__ void centroid_kernel(const float* __restrict__ e,
                                float* __restrict__ cent) {
    int gid = blockIdx.x * 256 + threadIdx.x;
    int n = gid >> 9;
    int d = gid & 511;
    const float* p = e + ((size_t)n * M_UTT) * D_EMB + d;
    float s = 0.f;
#pragma unroll
    for (int m = 0; m < M_UTT; ++m) s += p[(size_t)m * D_EMB];
    cent[gid] = s * (1.0f / M_UTT);
}

__global__ void normsq_kernel(const float* __restrict__ e,
                              float* __restrict__ nsq) {
    int wv = threadIdx.x >> 6;
    int lane = threadIdx.x & 63;
    int row = blockIdx.x * 4 + wv;
    const float* p = e + (size_t)row * D_EMB + lane;
    float s = 0.f;
#pragma unroll
    for (int j = 0; j < 8; ++j) { float x = p[j * 64]; s += x * x; }
#pragma unroll
    for (int off = 32; off; off >>= 1) s += __shfl_xor(s, off);
    if (lane == 0) nsq[row] = s;
}

#define BR 64
#define BC 128
#define BK 16
#define TR 4
#define TC 8

__global__ __launch_bounds__(256, 2)
void ge2e_main(const float* __restrict__ e, const float* __restrict__ cent,
               const float* __restrict__ nsq, const float* __restrict__ wp,
               const float* __restrict__ bp, float* __restrict__ partials) {
    __shared__ float As[BK][BR];
    __shared__ float Bs[BK][BC];
    __shared__ float diagLs[BR];
    __shared__ float red[16];

    const int tid = threadIdx.x;
    const int tx = tid & 15;
    const int ty = tid >> 4;
    const int blk = blockIdx.x;
    const int r0 = blk * BR;

    const float w = *wp;
    const float bb = *bp;

    float m_run[TR], s_run[TR];
#pragma unroll
    for (int i = 0; i < TR; ++i) { m_run[i] = NEG_INF; s_run[i] = 0.f; }

    const int a_row = tid >> 2;
    const int a_k   = (tid & 3) * 4;
    const int b_col = tid >> 1;
    const int b_k   = (tid & 1) * 8;

    for (int ct = 0; ct < N_SPK / BC; ++ct) {
        const int c0 = ct * BC;
        float acc[TR][TC];
#pragma unroll
        for (int i = 0; i < TR; ++i)
#pragma unroll
            for (int j = 0; j < TC; ++j) acc[i][j] = 0.f;

        for (int kk = 0; kk < D_EMB; kk += BK) {
            __syncthreads();
            {
                float4 av = *(const float4*)(e + (size_t)(r0 + a_row) * D_EMB + kk + a_k);
                As[a_k + 0][a_row] = av.x;
                As[a_k + 1][a_row] = av.y;
                As[a_k + 2][a_row] = av.z;
                As[a_k + 3][a_row] = av.w;
            }
            {
                const float* bp0 = cent + (size_t)(c0 + b_col) * D_EMB + kk + b_k;
                float4 bv0 = *(const float4*)(bp0);
                float4 bv1 = *(const float4*)(bp0 + 4);
                Bs[b_k + 0][b_col] = bv0.x;
                Bs[b_k + 1][b_col] = bv0.y;
                Bs[b_k + 2][b_col] = bv0.z;
                Bs[b_k + 3][b_col] = bv0.w;
                Bs[b_k + 4][b_col] = bv1.x;
                Bs[b_k + 5][b_col] = bv1.y;
                Bs[b_k + 6][b_col] = bv1.z;
                Bs[b_k + 7][b_col] = bv1.w;
            }
            __syncthreads();

#pragma unroll
            for (int k = 0; k < BK; ++k) {
                float4 a4 = *(const float4*)&As[k][ty * TR];
                float4 b4a = *(const float4*)&Bs[k][tx * TC];
                float4 b4b = *(const float4*)&Bs[k][tx * TC + 4];
                float av[TR] = {a4.x, a4.y, a4.z, a4.w};
                float bv[TC] = {b4a.x, b4a.y, b4a.z, b4a.w,
                                b4b.x, b4b.y, b4b.z, b4b.w};
#pragma unroll
                for (int i = 0; i < TR; ++i)
#pragma unroll
                    for (int j = 0; j < TC; ++j)
                        acc[i][j] = __builtin_fmaf(av[i], bv[j], acc[i][j]);
            }
        }

#pragma unroll
        for (int i = 0; i < TR; ++i) {
            const int grow = r0 + ty * TR + i;
            const int dcol = grow >> 5;
            float lv[TC];
#pragma unroll
            for (int j = 0; j < TC; ++j) {
                const int gcol = c0 + tx * TC + j;
                float v = acc[i][j];
                float lg;
                if (gcol == dcol) {
                    lg = __builtin_fmaf(w, __builtin_fmaf(32.0f, v,
                             (1.0f / 31.0f) * nsq[grow]), bb);
                    diagLs[ty * TR + i] = lg;
                } else {
                    lg = __builtin_fmaf(w, v, bb);
                }
                lv[j] = lg;
            }
            float mx = lv[0];
#pragma unroll
            for (int j = 1; j < TC; ++j) mx = fmaxf(mx, lv[j]);
#pragma unroll
            for (int off = 8; off; off >>= 1) mx = fmaxf(mx, __shfl_xor(mx, off));
            float ss = 0.f;
#pragma unroll
            for (int j = 0; j < TC; ++j) ss += __expf(lv[j] - mx);
#pragma unroll
            for (int off = 8; off; off >>= 1) ss += __shfl_xor(ss, off);
            float nm = fmaxf(m_run[i], mx);
            s_run[i] = s_run[i] * __expf(m_run[i] - nm) + ss * __expf(mx - nm);
            m_run[i] = nm;
        }
    }

    __syncthreads();
    if (tx == 0) {
        float part = 0.f;
#pragma unroll
        for (int i = 0; i < TR; ++i) {
            const int lr = ty * TR + i;
            part += m_run[i] + __logf(s_run[i]) - diagLs[lr];
        }
        red[ty] = part;
    }
    __syncthreads();
    if (tid == 0) {
        float t = 0.f;
#pragma unroll
        for (int i = 0; i < 16; ++i) t += red[i];
        partials[blk] = t;
    }
}

__global__ void reduce_kernel(const float* __restrict__ partials,
                              float* __restrict__ out) {
    __shared__ float red[4];
    int tid = threadIdx.x;
    float v = partials[tid] + partials[tid + 256];
#pragma unroll
    for (int off = 32; off; off >>= 1) v += __shfl_xor(v, off);
    if ((tid & 63) == 0) red[tid >> 6] = v;
    __syncthreads();
    if (tid == 0)
        out[0] = (red[0] + red[1] + red[2] + red[3]) * (1.0f / NROWS);
}

// ===========================================================================

extern "C" void kernel_launch(void* const* d_in, const int* in_sizes, int n_in,
                              void* d_out, int out_size, void* d_ws, size_t ws_size,
                              hipStream_t stream) {
    const float* e  = (const float*)d_in[0];   // [1024,32,512] f32
    const float* wp = (const float*)d_in[1];   // scalar
    const float* bp = (const float*)d_in[2];   // scalar
    float* out = (float*)d_out;

    // Fast-path workspace layout (bytes, 256-aligned):
    //   ehf 33554432 | ch 1048576 | dgl 131072 | pm 4194304
    const size_t NEED_FAST = 33554432ull + 1048576ull + 131072ull
                           + 4194304ull;   // 38,928,384

    if (ws_size >= NEED_FAST) {
        char* base = (char*)d_ws;
        _Float16* ehf = (_Float16*)(base);
        _Float16* ch  = (_Float16*)(base + 33554432ull);
        float*    dgl = (float*)   (base + 34603008ull);
        float2*   pm  = (float2*)  (base + 34734080ull);

        prep_kernel<<<N_SPK, 256, 0, stream>>>(e, ehf, ch, dgl, wp, bp, out);
        gemm_ls_kernel<<<2048, 256, 0, stream>>>(ehf, ch, dgl, wp, bp, pm);
        rowloss_kernel<<<NROWS / 256, 256, 0, stream>>>(pm, dgl, out);
    } else {
        float* ws = (float*)d_ws;
        float* cent     = ws;
        float* nsq      = ws + 524288;
        float* partials = ws + 524288 + 32768;

        centroid_kernel<<<N_SPK * D_EMB / 256, 256, 0, stream>>>(e, cent);
        normsq_kernel<<<NROWS / 4, 256, 0, stream>>>(e, nsq);
        ge2e_main<<<NROWS / BR, 256, 0, stream>>>(e, cent, nsq, wp, bp, partials);
        reduce_kernel<<<1, 256, 0, stream>>>(partials, out);
    }
}